// Round 4
// baseline (331.926 us; speedup 1.0000x reference)
//
#include <hip/hip_runtime.h>

// Correlation1D on MI355X (gfx950), round 8 (= R7 resubmitted; the R7 bench
// died in infra — "container failed twice" — with no kernel verdict).
// out[b,d,h,w] = (1/256) * sum_c in1[b,c,h,w] * in2[b,c,h,w+d-40]
// B=8 C=256 H=96 W=192 D=81 PAD=40.
//
// Theory under test: R4/R5/R6 all pinned at 126us = 3.9 B/cy/CU of staging
// delivery, invariant to schedule and instruction width -> the glds
// (global_load_lds) path appears throughput-capped in the cache-MISS regime
// (learn_hip glds wins were L2-warm; m13's 6.3 TB/s stream used register
// loads; HipKittens reg-stages). This kernel uses T14 reg-staging:
// global_load_dwordx4 -> VGPR (2 chunks deep, 12 loads in flight/wave) ->
// ds_write_b128, issue-early/write-late, counted vmcnt(6). SR=196 padded
// rows (784 B = 16B-aligned for b128; 4-bank shift/row -> reads & writes
// <=2-way bank-aliased = free).

typedef __attribute__((ext_vector_type(8))) short short8;     // 8 bf16
typedef __attribute__((ext_vector_type(4))) short short4v;    // 4 bf16
typedef __attribute__((ext_vector_type(4))) float float4v;

#if defined(__has_builtin)
#if __has_builtin(__builtin_amdgcn_mfma_f32_16x16x16bf16_1k)
#define HAVE_MFMA16 1
#endif
#endif
#ifndef HAVE_MFMA16
#define HAVE_MFMA16 0
#endif

__device__ __forceinline__ unsigned short f2bf(float f) {
  // round-to-nearest-even fp32 -> bf16
  unsigned int u = __float_as_uint(f);
  return (unsigned short)((u + 0x7FFFu + ((u >> 16) & 1u)) >> 16);
}

__global__ __launch_bounds__(256, 3) void corr1d_kernel(
    const float* __restrict__ in1, const float* __restrict__ in2,
    float* __restrict__ out) {
  constexpr int W = 192, H = 96, C = 256, D = 81;
  constexpr int HW = H * W;          // c-stride in elements
  constexpr int KC = 16;             // channels per chunk (16 chunks)
  constexpr int SR = 196;            // LDS row stride: 784 B (16B-aligned)
  constexpr int ES = 196;            // epilogue row stride
  constexpr int BUF = KC * SR;       // floats per array per buffer (3136)

  // LDS: 2 ping-pong buffers x (A[16][196] + B[16][196]) fp32 = 50,176 B
  // -> 3 blocks/CU (150,528 <= 160 KiB). Epilogue overlays E[41][196].
  __shared__ __align__(16) float smem[4 * BUF];
  float* E = smem;

  const int bh = blockIdx.x;
  const int b = bh / H, h = bh % H;
  const int tid = threadIdx.x;
  const int lane = tid & 63;
  const int wv = tid >> 6;           // wave 0..3, owns w-tiles 3wv..3wv+2
  const int l15 = lane & 15, lq = lane >> 4;
  const int base = (b * C * H + h) * W;

  float4v acc[3][6];
#pragma unroll
  for (int i = 0; i < 3; ++i)
#pragma unroll
    for (int jj = 0; jj < 6; ++jj) acc[i][jj] = (float4v){0.f, 0.f, 0.f, 0.f};

  // ---- per-lane staging geometry: wave wv owns rows 4wv..4wv+3 of each
  // array per chunk (768 floats each). Group g covers floats [256g,256g+256)
  // of the wave's region; lane takes the float4 at 256g+4*lane.
  int soff[3], loff[3];
#pragma unroll
  for (int g = 0; g < 3; ++g) {
    const int fidx = 256 * g + 4 * lane;   // 0..1020
    const int r = fidx / 192;              // row within the wave's 4
    const int col = fidx - 192 * r;
    soff[g] = (4 * wv + r) * HW + col;     // global (contiguous rows)
    loff[g] = (4 * wv + r) * SR + col;     // LDS (padded rows)
  }
  const float* in1p = in1 + base;
  const float* in2p = in2 + base;

  // ---- two named register sets (static indexing; rule #20).
  float4v rA0[3], rB0[3], rA1[3], rB1[3];
  auto LOAD0 = [&](int m) {
    const float* g1 = in1p + KC * m * HW;
    const float* g2 = in2p + KC * m * HW;
#pragma unroll
    for (int g = 0; g < 3; ++g) {
      rA0[g] = *(const float4v*)(g1 + soff[g]);
      rB0[g] = *(const float4v*)(g2 + soff[g]);
    }
  };
  auto LOAD1 = [&](int m) {
    const float* g1 = in1p + KC * m * HW;
    const float* g2 = in2p + KC * m * HW;
#pragma unroll
    for (int g = 0; g < 3; ++g) {
      rA1[g] = *(const float4v*)(g1 + soff[g]);
      rB1[g] = *(const float4v*)(g2 + soff[g]);
    }
  };
  auto WRITE0 = [&]() {            // even chunks -> buffer 0
    float* As = smem;
    float* Bs = smem + BUF;
#pragma unroll
    for (int g = 0; g < 3; ++g) {
      *(float4v*)(As + loff[g]) = rA0[g];
      *(float4v*)(Bs + loff[g]) = rB0[g];
    }
  };
  auto WRITE1 = [&]() {            // odd chunks -> buffer 1
    float* As = smem + 2 * BUF;
    float* Bs = smem + 3 * BUF;
#pragma unroll
    for (int g = 0; g < 3; ++g) {
      *(float4v*)(As + loff[g]) = rA1[g];
      *(float4v*)(Bs + loff[g]) = rB1[g];
    }
  };

  // ---- compute chunk resident in buffer p (fp32 LDS -> bf16 regs + banded
  // MFMA; 18 MFMAs per wave per chunk).
  auto compute_chunk = [&](int p) {
    const float* As = smem + p * (2 * BUF);
    const float* Bs = As + BUF;
#if HAVE_MFMA16
    short4v af[3];
#pragma unroll
    for (int i = 0; i < 3; ++i) {
      const float* ap = As + 48 * wv + 16 * i + l15;
      unsigned short o[4];
#pragma unroll
      for (int t = 0; t < 4; ++t) o[t] = f2bf(ap[(4 * lq + t) * SR]);
      af[i] = *(const short4v*)o;
    }
#pragma unroll
    for (int jt = 0; jt < 8; ++jt) {
      const int j = 16 * (3 * wv + jt) + l15;     // padded j coord
      const bool ok = (j >= 40) && (j < 232);     // in2 col = j-40
      const float* bp = Bs + (ok ? (j - 40) : 0);
      unsigned short o[4];
#pragma unroll
      for (int t = 0; t < 4; ++t) {
        float v = ok ? bp[(4 * lq + t) * SR] : 0.0f;
        o[t] = f2bf(v);
      }
      short4v bfr = *(const short4v*)o;
#pragma unroll
      for (int i = 0; i < 3; ++i) {
        const int jj = jt - i;                    // compile-time after unroll
        if (jj >= 0 && jj < 6)
          acc[i][jj] = __builtin_amdgcn_mfma_f32_16x16x16bf16_1k(
              af[i], bfr, acc[i][jj], 0, 0, 0);
      }
    }
#else
    // Fallback: zero-padded 16x16x32 (upper 16 k-lanes contribute zeros).
    const bool okq = (lq < 2);
    const int rb = okq ? 8 * lq : 0;
    short8 af[3];
#pragma unroll
    for (int i = 0; i < 3; ++i) {
      const float* ap = As + 48 * wv + 16 * i + l15;
      unsigned short o[8];
#pragma unroll
      for (int t = 0; t < 8; ++t) {
        float v = ap[(rb + t) * SR];
        o[t] = okq ? f2bf(v) : (unsigned short)0;
      }
      af[i] = *(const short8*)o;
    }
#pragma unroll
    for (int jt = 0; jt < 8; ++jt) {
      const int j = 16 * (3 * wv + jt) + l15;
      const bool ok = (j >= 40) && (j < 232);
      const float* bp = Bs + (ok ? (j - 40) : 0);
      unsigned short o[8];
#pragma unroll
      for (int t = 0; t < 8; ++t) {
        float v = bp[(rb + t) * SR];
        o[t] = (ok && okq) ? f2bf(v) : (unsigned short)0;
      }
      short8 bfr = *(const short8*)o;
#pragma unroll
      for (int i = 0; i < 3; ++i) {
        const int jj = jt - i;
        if (jj >= 0 && jj < 6)
          acc[i][jj] = __builtin_amdgcn_mfma_f32_16x16x32_bf16(
              af[i], bfr, acc[i][jj], 0, 0, 0);
      }
    }
#endif
  };

  // ---- software-pipelined main loop, 2-chunk-deep register prefetch.
  // Steady state per chunk m: {compute(m); barrier; vmcnt(6) [chunk m+1's 6
  // loads done, m+2's still in flight]; ds_write chunk m+1; issue loads for
  // chunk m+3; lgkmcnt(0); barrier}. All waits/barriers are wave-uniform.
  LOAD0(0);
  LOAD1(1);
  asm volatile("s_waitcnt vmcnt(6)" ::: "memory");   // chunk 0 loaded
  WRITE0();
  LOAD0(2);
  asm volatile("s_waitcnt lgkmcnt(0)" ::: "memory");
  __builtin_amdgcn_s_barrier();
#pragma unroll 1
  for (int t = 0; t < 7; ++t) {                      // chunks 0..13
    const int m = 2 * t;
    compute_chunk(0);                                // chunk m
    __builtin_amdgcn_s_barrier();
    asm volatile("s_waitcnt vmcnt(6)" ::: "memory"); // chunk m+1 loaded
    WRITE1();
    if (m + 3 < 16) LOAD1(m + 3);
    asm volatile("s_waitcnt lgkmcnt(0)" ::: "memory");
    __builtin_amdgcn_s_barrier();
    compute_chunk(1);                                // chunk m+1
    __builtin_amdgcn_s_barrier();
    asm volatile("s_waitcnt vmcnt(6)" ::: "memory"); // chunk m+2 loaded
    WRITE0();
    if (m + 4 < 16) LOAD0(m + 4);
    asm volatile("s_waitcnt lgkmcnt(0)" ::: "memory");
    __builtin_amdgcn_s_barrier();
  }
  compute_chunk(0);                                  // chunk 14
  __builtin_amdgcn_s_barrier();
  asm volatile("s_waitcnt vmcnt(0)" ::: "memory");   // chunk 15 loaded
  WRITE1();
  asm volatile("s_waitcnt lgkmcnt(0)" ::: "memory");
  __builtin_amdgcn_s_barrier();
  compute_chunk(1);                                  // chunk 15

  // ---- epilogue: D layout col(j)=l15, row(w)=4lq+r -> d = 16jj+l15-4lq-r.
  // Two d-phases through LDS overlay; full-row float4 coalesced stores.
  const float scale = 1.0f / 256.0f;
#pragma unroll
  for (int p = 0; p < 2; ++p) {
    const int dlo = p ? 41 : 0;
    const int nd  = p ? 40 : 41;
    __syncthreads();                 // buffers / previous E free
#pragma unroll
    for (int i = 0; i < 3; ++i)
#pragma unroll
      for (int jj = 0; jj < 6; ++jj)
#pragma unroll
        for (int r = 0; r < 4; ++r) {
          const int d = 16 * jj + l15 - 4 * lq - r;
          const int w = 48 * wv + 16 * i + 4 * lq + r;
          if (d >= dlo && d < dlo + nd)
            E[(d - dlo) * ES + w] = acc[i][jj][r] * scale;
        }
    __syncthreads();
    for (int t = tid; t < nd * 48; t += 256) {
      const int dr = t / 48, g = t % 48;
      float4v val = *(const float4v*)(E + dr * ES + 4 * g);
      *(float4v*)(out + ((b * D + dlo + dr) * H + h) * W + 4 * g) = val;
    }
  }
}

extern "C" void kernel_launch(void* const* d_in, const int* in_sizes, int n_in,
                              void* d_out, int out_size, void* d_ws, size_t ws_size,
                              hipStream_t stream) {
  const float* in1 = (const float*)d_in[0];
  const float* in2 = (const float*)d_in[1];
  float* out = (float*)d_out;
  (void)in_sizes; (void)n_in; (void)out_size; (void)d_ws; (void)ws_size;
  corr1d_kernel<<<dim3(768), dim3(256), 0, stream>>>(in1, in2, out);
}